// Round 7
// baseline (230.833 us; speedup 1.0000x reference)
//
#include <hip/hip_runtime.h>
#include <hip/hip_bf16.h>
#include <hip/hip_fp16.h>

#define N_NODES 16384
#define N_EDGES 262144
#define MUL 32
// padded records capacity: N_EDGES + 3*N_NODES + 16 tail
#define REC_CAP (N_EDGES + 3 * N_NODES + 16)

__device__ __forceinline__ float silu_f(float x) {
    return x / (1.0f + __expf(-x));
}
__device__ __forceinline__ __half2 i2h2(int v) { return __builtin_bit_cast(__half2, v); }
__device__ __forceinline__ int h22i(__half2 v) { return __builtin_bit_cast(int, v); }

// ---------------- K1: per-node up projection (f16 out, channel-major float4 layout)
//                 + fused receiver histogram with rank capture (32 edges / block) ----
__global__ void k_up(const float* __restrict__ nf,
                     const float* __restrict__ Wus,
                     const float* __restrict__ Wuv,
                     __half* __restrict__ up_h,
                     const int* __restrict__ recv,
                     int* __restrict__ counts,
                     int* __restrict__ rank) {
    __shared__ float sh[2][128];
    int node0 = blockIdx.x * 2;
    int t = threadIdx.x;                       // 0..255
    if (t < 32) {
        int e = blockIdx.x * 32 + t;
        rank[e] = atomicAdd(&counts[recv[e]], 1);
    }
    sh[t >> 7][t & 127] = nf[(size_t)node0 * 128 + t];
    __syncthreads();
    int local = t >> 7;
    int c = t & 127;
    int m = c >> 2, comp = c & 3;
    const float* row = sh[local];
    float acc = 0.f;
    if (comp == 0) {
        #pragma unroll
        for (int k = 0; k < 32; ++k) acc += row[k] * Wus[k * 32 + m];
    } else {
        int i = comp - 1;
        #pragma unroll
        for (int k = 0; k < 32; ++k) acc += row[32 + k * 3 + i] * Wuv[k * 32 + m];
    }
    up_h[(size_t)(node0 + local) * 128 + c] = __float2half(acc * 0.17677669529663687f);
}

// ---------------- K2: exclusive scan of counts padded to multiple of 4 -> starts ----
__global__ void k_scan(const int* __restrict__ counts,
                       int* __restrict__ starts) {
    __shared__ int wtot[16];
    __shared__ int woff[16];
    int t = threadIdx.x;          // 0..1023
    int lane = t & 63, wid = t >> 6;
    const int4* cp = (const int4*)(counts + t * 16);
    int4 c0 = cp[0], c1 = cp[1], c2 = cp[2], c3 = cp[3];
    int cs[16] = {c0.x,c0.y,c0.z,c0.w,c1.x,c1.y,c1.z,c1.w,
                  c2.x,c2.y,c2.z,c2.w,c3.x,c3.y,c3.z,c3.w};
    int mysum = 0;
    #pragma unroll
    for (int i = 0; i < 16; ++i) {
        cs[i] = (cs[i] + 3) & ~3;     // pad each node to multiple of 4
        mysum += cs[i];
    }
    int incl = mysum;
    #pragma unroll
    for (int off = 1; off < 64; off <<= 1) {
        int y = __shfl_up(incl, off, 64);
        if (lane >= off) incl += y;
    }
    if (lane == 63) wtot[wid] = incl;
    __syncthreads();
    if (t == 0) {
        int run = 0;
        #pragma unroll
        for (int w = 0; w < 16; ++w) { woff[w] = run; run += wtot[w]; }
    }
    __syncthreads();
    int run = woff[wid] + (incl - mysum);
    #pragma unroll
    for (int i = 0; i < 16; ++i) {
        starts[t * 16 + i] = run;
        run += cs[i];
    }
    if (t == 1023) starts[N_NODES] = run;
}

// ---------------- K3: fused radial MLP + scatter (atomic-free via rank) ----------
// record (8 ints): [snd][y01 h2][y2_ h2][0] [h01][h23][h45][h67]
// Also zeroes pad slots (between counts[n] and padded end) and the 16-record tail.
__global__ void k_edges(const float* __restrict__ rad,
                        const float* __restrict__ Wr1,
                        const int* __restrict__ recv,
                        const int* __restrict__ senders,
                        const float* __restrict__ esh,
                        const int* __restrict__ starts,
                        const int* __restrict__ counts,
                        const int* __restrict__ rank,
                        int4* __restrict__ records) {
    int e = blockIdx.x * blockDim.x + threadIdx.x;
    const int4 z = make_int4(0, 0, 0, 0);

    // zero pad slots of node e (<=3 per node)
    if (e < N_NODES) {
        int st = starts[e] + counts[e];
        int en = starts[e + 1];
        for (int p = st; p < en; ++p) {
            records[2 * (size_t)p] = z;
            records[2 * (size_t)p + 1] = z;
        }
    }
    if (e < 16) {
        int total = starts[N_NODES];
        records[2 * (size_t)(total + e)] = z;
        records[2 * (size_t)(total + e) + 1] = z;
    }

    const float4* rp = (const float4*)(rad + (size_t)e * 8);
    float4 a = rp[0], b = rp[1];
    float r[8] = {a.x, a.y, a.z, a.w, b.x, b.y, b.z, b.w};
    float h[8];
    #pragma unroll
    for (int j = 0; j < 8; ++j) {
        float acc = 0.f;
        #pragma unroll
        for (int k = 0; k < 8; ++k) acc += r[k] * Wr1[k * 8 + j];
        h[j] = silu_f(acc * 0.35355339059327373f);  // 1/sqrt(8)
    }
    float4 ey = *(const float4*)(esh + (size_t)e * 4);
    int snd = senders[e];
    int rc = recv[e];
    int pos = starts[rc] + rank[e];
    int4 meta;
    meta.x = snd;
    meta.y = h22i(__floats2half2_rn(ey.y, ey.z));
    meta.z = h22i(__floats2half2_rn(ey.w, 0.f));
    meta.w = 0;
    int4 hp;
    hp.x = h22i(__floats2half2_rn(h[0], h[1]));
    hp.y = h22i(__floats2half2_rn(h[2], h[3]));
    hp.z = h22i(__floats2half2_rn(h[4], h[5]));
    hp.w = h22i(__floats2half2_rn(h[6], h[7]));
    records[2 * (size_t)pos] = meta;
    records[2 * (size_t)pos + 1] = hp;
}

// ---------------- per-edge accumulate helper ----------------
struct Acc {
    float S0, S1, Vv0, Vv1, Vv2, Vt0, Vt1, Vt2;
};
__device__ __forceinline__ void edge_accum(int4 meta, int4 hp, int2 q,
                                           const float* __restrict__ wr2a,
                                           const float* __restrict__ wr2b,
                                           const float* __restrict__ wr2c,
                                           const float* __restrict__ wr2d,
                                           Acc& A) {
    float2 h01 = __half22float2(i2h2(hp.x));
    float2 h23 = __half22float2(i2h2(hp.y));
    float2 h45 = __half22float2(i2h2(hp.z));
    float2 h67 = __half22float2(i2h2(hp.w));
    float h[8] = {h01.x, h01.y, h23.x, h23.y, h45.x, h45.y, h67.x, h67.y};
    float wss = 0.f, wvs = 0.f, wvt = 0.f, wst = 0.f;
    #pragma unroll
    for (int j = 0; j < 8; ++j) {
        wss += h[j] * wr2a[j];
        wvs += h[j] * wr2b[j];
        wvt += h[j] * wr2c[j];
        wst += h[j] * wr2d[j];
    }
    float2 y01 = __half22float2(i2h2(meta.y));
    float2 y2p = __half22float2(i2h2(meta.z));
    float y0 = y01.x, y1 = y01.y, y2 = y2p.x;
    float2 sv0 = __half22float2(i2h2(q.x));
    float2 v12 = __half22float2(i2h2(q.y));
    float ss = sv0.x, v0 = sv0.y, v1v = v12.x, v2 = v12.y;
    float dot = v0 * y0 + v1v * y1 + v2 * y2;
    A.S0 += ss * wss;
    A.S1 += dot * wst;
    A.Vv0 += v0 * wvs; A.Vv1 += v1v * wvs; A.Vv2 += v2 * wvs;
    float tv = ss * wvt;
    A.Vt0 += tv * y0; A.Vt1 += tv * y1; A.Vt2 += tv * y2;
}

// ---------------- K4: fused gather + message + down-proj + skip + gate ----------------
// One wave per node, 4 edges per iteration, predicate-free (edge lists padded to
// x4 with zero records; 16-record zero tail covers prefetch overrun). Two-stage
// software pipeline: records 2 iters ahead, up-rows 1 iter ahead. Barrier-free.
__launch_bounds__(256, 4)
__global__ void k_gather(const __half* __restrict__ up_h,
                         const float* __restrict__ nf,
                         const int4* __restrict__ records,
                         const float* __restrict__ Wr2,
                         const int* __restrict__ starts,
                         const float* __restrict__ Wdns,
                         const float* __restrict__ Wdnv,
                         const float* __restrict__ Wsks,
                         const float* __restrict__ Wskv,
                         const int* __restrict__ species,
                         float* __restrict__ out) {
    __shared__ float agg[4][256];    // per node: S[64] then V[64][3] (m-major)
    __shared__ float snode[4][32];
    __shared__ float vnode[4][96];

    int tid = threadIdx.x;
    int w = tid >> 6;          // node slot 0..3 (== wave id)
    int lane = tid & 63;
    int sub = lane >> 5;       // edge sub-slot
    int m = lane & 31;         // channel
    int node = blockIdx.x * 4 + w;

    int s0 = starts[node], s1 = starts[node + 1];

    // ---- pipeline preheader (all loads unconditional; zero tail keeps them safe)
    int ta = s0 + sub;
    const int4* rp;
    rp = records + 2 * (size_t)ta;        int4 c0 = rp[0], c1 = rp[1];
    rp = records + 2 * (size_t)(ta + 2);  int4 d0 = rp[0], d1 = rp[1];

    // stage this wave's node_features for the skip connection (same-wave LDS)
    {
        const float* src = nf + (size_t)node * 128;
        #pragma unroll
        for (int it = 0; it < 2; ++it) {
            int c = lane + it * 64;
            float v = src[c];
            if (c < 32) snode[w][c] = v;
            else        vnode[w][c - 32] = v;
        }
    }

    int2 qa = *(const int2*)(up_h + (size_t)c0.x * 128 + m * 4);
    int2 qb = *(const int2*)(up_h + (size_t)d0.x * 128 + m * 4);

    rp = records + 2 * (size_t)(ta + 4);  int4 n0 = rp[0], n1 = rp[1];
    rp = records + 2 * (size_t)(ta + 6);  int4 e0 = rp[0], e1 = rp[1];

    // hoist Wr2 columns into registers; fold 1/sqrt(8) (and 1/sqrt(3) for wst)
    const float s8 = 0.35355339059327373f;
    const float s8s3 = 0.35355339059327373f * 0.5773502691896258f;
    float wr2a[8], wr2b[8], wr2c[8], wr2d[8];
    #pragma unroll
    for (int j = 0; j < 8; ++j) {
        wr2a[j] = Wr2[j * 128 + m] * s8;
        wr2b[j] = Wr2[j * 128 + 32 + m] * s8;
        wr2c[j] = Wr2[j * 128 + 64 + m] * s8;
        wr2d[j] = Wr2[j * 128 + 96 + m] * s8s3;
    }

    Acc A = {0.f,0.f,0.f,0.f,0.f,0.f,0.f,0.f};
    Acc B = {0.f,0.f,0.f,0.f,0.f,0.f,0.f,0.f};

    #pragma unroll 2
    for (int t0 = s0; t0 < s1; t0 += 4) {
        // up-row loads for next iteration (records already resident)
        int2 qna = *(const int2*)(up_h + (size_t)n0.x * 128 + m * 4);
        int2 qnb = *(const int2*)(up_h + (size_t)e0.x * 128 + m * 4);

        // record loads for iteration after next (may read zero tail — safe)
        int t2 = t0 + 8 + sub;
        rp = records + 2 * (size_t)t2;        int4 p0 = rp[0], p1 = rp[1];
        rp = records + 2 * (size_t)(t2 + 2);  int4 r0 = rp[0], r1 = rp[1];

        // compute current iteration (all operands already in registers)
        edge_accum(c0, c1, qa, wr2a, wr2b, wr2c, wr2d, A);
        edge_accum(d0, d1, qb, wr2a, wr2b, wr2c, wr2d, B);

        // rotate pipeline (unroll-2 lets the compiler rename most of these away)
        c0 = n0; c1 = n1; d0 = e0; d1 = e1;
        qa = qna; qb = qnb;
        n0 = p0; n1 = p1; e0 = r0; e1 = r1;
    }

    float accS0 = A.S0 + B.S0, accS1 = A.S1 + B.S1;
    float accVv0 = A.Vv0 + B.Vv0, accVv1 = A.Vv1 + B.Vv1, accVv2 = A.Vv2 + B.Vv2;
    float accVt0 = A.Vt0 + B.Vt0, accVt1 = A.Vt1 + B.Vt1, accVt2 = A.Vt2 + B.Vt2;

    // combine the two edge sub-slots
    accS0 += __shfl_xor(accS0, 32, 64);
    accS1 += __shfl_xor(accS1, 32, 64);
    accVv0 += __shfl_xor(accVv0, 32, 64);
    accVv1 += __shfl_xor(accVv1, 32, 64);
    accVv2 += __shfl_xor(accVv2, 32, 64);
    accVt0 += __shfl_xor(accVt0, 32, 64);
    accVt1 += __shfl_xor(accVt1, 32, 64);
    accVt2 += __shfl_xor(accVt2, 32, 64);

    const float inv_neigh = 0.25f;   // AVG_NEIGH^-0.5
    if (sub == 0) {
        agg[w][m]               = accS0 * inv_neigh;
        agg[w][32 + m]          = accS1 * inv_neigh;
        agg[w][64 + 3 * m + 0]  = accVv0 * inv_neigh;
        agg[w][64 + 3 * m + 1]  = accVv1 * inv_neigh;
        agg[w][64 + 3 * m + 2]  = accVv2 * inv_neigh;
        agg[w][160 + 3 * m + 0] = accVt0 * inv_neigh;
        agg[w][160 + 3 * m + 1] = accVt1 * inv_neigh;
        agg[w][160 + 3 * m + 2] = accVt2 * inv_neigh;
    }
    // same-wave LDS write->read: ordered per wave, no barrier needed

    const float* S = agg[w];
    const float* V = agg[w] + 64;
    int sp = species[node];

    // down projection split across the two half-waves (mm ranges), combined via shfl
    float gsa = 0.f, gsb = 0.f, gv0 = 0.f, gv1 = 0.f, gv2 = 0.f;
    {
        int mm0 = sub * 32;
        #pragma unroll 4
        for (int k = 0; k < 32; ++k) {
            int mm = mm0 + k;
            float Sm = S[mm];
            gsa += Sm * Wdns[mm * 64 + m];
            gsb += Sm * Wdns[mm * 64 + 32 + m];
            float wv = Wdnv[mm * 32 + m];
            gv0 += V[mm * 3 + 0] * wv;
            gv1 += V[mm * 3 + 1] * wv;
            gv2 += V[mm * 3 + 2] * wv;
        }
    }
    float ska = 0.f, skb = 0.f, skv0 = 0.f, skv1 = 0.f, skv2 = 0.f;
    {
        const float* Ws = Wsks + (size_t)sp * 2048;   // [32][64]
        const float* Wv = Wskv + (size_t)sp * 1024;   // [32][32]
        int mm0 = sub * 16;
        #pragma unroll 4
        for (int k = 0; k < 16; ++k) {
            int mm = mm0 + k;
            float sm = snode[w][mm];
            ska += sm * Ws[mm * 64 + m];
            skb += sm * Ws[mm * 64 + 32 + m];
            float wv = Wv[mm * 32 + m];
            skv0 += vnode[w][mm * 3 + 0] * wv;
            skv1 += vnode[w][mm * 3 + 1] * wv;
            skv2 += vnode[w][mm * 3 + 2] * wv;
        }
    }
    gsa += __shfl_xor(gsa, 32, 64);
    gsb += __shfl_xor(gsb, 32, 64);
    gv0 += __shfl_xor(gv0, 32, 64);
    gv1 += __shfl_xor(gv1, 32, 64);
    gv2 += __shfl_xor(gv2, 32, 64);
    ska += __shfl_xor(ska, 32, 64);
    skb += __shfl_xor(skb, 32, 64);
    skv0 += __shfl_xor(skv0, 32, 64);
    skv1 += __shfl_xor(skv1, 32, 64);
    skv2 += __shfl_xor(skv2, 32, 64);

    if (sub == 0) {
        const float inv8 = 0.125f;                 // (2*MUL)^-0.5
        const float isq32 = 0.17677669529663687f;  // 1/sqrt(32)
        float a  = 0.5f * (gsa * inv8 + ska * isq32);
        float b  = 0.5f * (gsb * inv8 + skb * isq32);
        float o0 = 0.5f * (gv0 * inv8 + skv0 * isq32);
        float o1 = 0.5f * (gv1 * inv8 + skv1 * isq32);
        float o2 = 0.5f * (gv2 * inv8 + skv2 * isq32);

        float feat = silu_f(a);
        float gate = silu_f(b);
        float* o = out + (size_t)node * 128;
        o[m] = feat;
        o[32 + 3 * m + 0] = o0 * gate;
        o[32 + 3 * m + 1] = o1 * gate;
        o[32 + 3 * m + 2] = o2 * gate;
    }
}

extern "C" void kernel_launch(void* const* d_in, const int* in_sizes, int n_in,
                              void* d_out, int out_size, void* d_ws, size_t ws_size,
                              hipStream_t stream) {
    const float* nf   = (const float*)d_in[0];
    const float* esh  = (const float*)d_in[1];
    const float* rad  = (const float*)d_in[2];
    const float* Wus  = (const float*)d_in[3];
    const float* Wuv  = (const float*)d_in[4];
    const float* Wr1  = (const float*)d_in[5];
    const float* Wr2  = (const float*)d_in[6];
    const float* Wdns = (const float*)d_in[7];
    const float* Wdnv = (const float*)d_in[8];
    const float* Wsks = (const float*)d_in[9];
    const float* Wskv = (const float*)d_in[10];
    const int* senders   = (const int*)d_in[11];
    const int* receivers = (const int*)d_in[12];
    const int* species   = (const int*)d_in[13];
    float* out = (float*)d_out;

    // workspace layout (bytes)
    char* ws = (char*)d_ws;
    __half* up_h   = (__half*)(ws);                       // 16384*128 f16   = 4 MB
    int4* records  = (int4*)(ws + (4u << 20));            // REC_CAP*32 B    ~ 10 MB
    int* counts    = (int*)(ws + (14u << 20));            // 64 KB
    int* starts    = (int*)(ws + (14u << 20) + 65536);    // 64 KB + 4
    int* rank      = (int*)(ws + (15u << 20));            // 1 MB

    hipMemsetAsync(counts, 0, 65536, stream);
    k_up<<<N_NODES / 2, 256, 0, stream>>>(nf, Wus, Wuv, up_h, receivers, counts, rank);
    k_scan<<<1, 1024, 0, stream>>>(counts, starts);
    k_edges<<<N_EDGES / 256, 256, 0, stream>>>(rad, Wr1, receivers, senders, esh,
                                               starts, counts, rank, records);
    k_gather<<<N_NODES / 4, 256, 0, stream>>>(up_h, nf, records, Wr2, starts,
                                              Wdns, Wdnv, Wsks, Wskv, species, out);
}

// Round 8
// 172.498 us; speedup vs baseline: 1.3382x; 1.3382x over previous
//
#include <hip/hip_runtime.h>
#include <hip/hip_bf16.h>
#include <hip/hip_fp16.h>

#define N_NODES 16384
#define N_EDGES 262144
#define MUL 32
// padded records capacity: N_EDGES + 3*N_NODES + 16 tail
#define REC_CAP (N_EDGES + 3 * N_NODES + 16)

__device__ __forceinline__ float silu_f(float x) {
    return x / (1.0f + __expf(-x));
}
__device__ __forceinline__ __half2 i2h2(int v) { return __builtin_bit_cast(__half2, v); }
__device__ __forceinline__ int h22i(__half2 v) { return __builtin_bit_cast(int, v); }

// ---------------- K1: per-node up projection (f16 out, channel-major float4 layout)
//                 + fused receiver histogram with rank capture (32 edges / block) ----
__global__ void k_up(const float* __restrict__ nf,
                     const float* __restrict__ Wus,
                     const float* __restrict__ Wuv,
                     __half* __restrict__ up_h,
                     const int* __restrict__ recv,
                     int* __restrict__ counts,
                     int* __restrict__ rank) {
    __shared__ float sh[2][128];
    int node0 = blockIdx.x * 2;
    int t = threadIdx.x;                       // 0..255
    if (t < 32) {
        int e = blockIdx.x * 32 + t;
        rank[e] = atomicAdd(&counts[recv[e]], 1);
    }
    sh[t >> 7][t & 127] = nf[(size_t)node0 * 128 + t];
    __syncthreads();
    int local = t >> 7;
    int c = t & 127;
    int m = c >> 2, comp = c & 3;
    const float* row = sh[local];
    float acc = 0.f;
    if (comp == 0) {
        #pragma unroll
        for (int k = 0; k < 32; ++k) acc += row[k] * Wus[k * 32 + m];
    } else {
        int i = comp - 1;
        #pragma unroll
        for (int k = 0; k < 32; ++k) acc += row[32 + k * 3 + i] * Wuv[k * 32 + m];
    }
    up_h[(size_t)(node0 + local) * 128 + c] = __float2half(acc * 0.17677669529663687f);
}

// ---------------- K2: exclusive scan of counts padded to multiple of 4 -> starts ----
__global__ void k_scan(const int* __restrict__ counts,
                       int* __restrict__ starts) {
    __shared__ int wtot[16];
    __shared__ int woff[16];
    int t = threadIdx.x;          // 0..1023
    int lane = t & 63, wid = t >> 6;
    const int4* cp = (const int4*)(counts + t * 16);
    int4 c0 = cp[0], c1 = cp[1], c2 = cp[2], c3 = cp[3];
    int cs[16] = {c0.x,c0.y,c0.z,c0.w,c1.x,c1.y,c1.z,c1.w,
                  c2.x,c2.y,c2.z,c2.w,c3.x,c3.y,c3.z,c3.w};
    int mysum = 0;
    #pragma unroll
    for (int i = 0; i < 16; ++i) {
        cs[i] = (cs[i] + 3) & ~3;     // pad each node to multiple of 4
        mysum += cs[i];
    }
    int incl = mysum;
    #pragma unroll
    for (int off = 1; off < 64; off <<= 1) {
        int y = __shfl_up(incl, off, 64);
        if (lane >= off) incl += y;
    }
    if (lane == 63) wtot[wid] = incl;
    __syncthreads();
    if (t == 0) {
        int run = 0;
        #pragma unroll
        for (int w = 0; w < 16; ++w) { woff[w] = run; run += wtot[w]; }
    }
    __syncthreads();
    int run = woff[wid] + (incl - mysum);
    #pragma unroll
    for (int i = 0; i < 16; ++i) {
        starts[t * 16 + i] = run;
        run += cs[i];
    }
    if (t == 1023) starts[N_NODES] = run;
}

// ---------------- K3: fused radial MLP + scatter (atomic-free via rank) ----------
// record (8 ints): [snd][y01 h2][y2_ h2][0] [h01][h23][h45][h67]
// Also zeroes pad slots (between counts[n] and padded end) and the 16-record tail.
__global__ void k_edges(const float* __restrict__ rad,
                        const float* __restrict__ Wr1,
                        const int* __restrict__ recv,
                        const int* __restrict__ senders,
                        const float* __restrict__ esh,
                        const int* __restrict__ starts,
                        const int* __restrict__ counts,
                        const int* __restrict__ rank,
                        int4* __restrict__ records) {
    int e = blockIdx.x * blockDim.x + threadIdx.x;
    const int4 z = make_int4(0, 0, 0, 0);

    // zero pad slots of node e (<=3 per node)
    if (e < N_NODES) {
        int st = starts[e] + counts[e];
        int en = starts[e + 1];
        for (int p = st; p < en; ++p) {
            records[2 * (size_t)p] = z;
            records[2 * (size_t)p + 1] = z;
        }
    }
    if (e < 16) {
        int total = starts[N_NODES];
        records[2 * (size_t)(total + e)] = z;
        records[2 * (size_t)(total + e) + 1] = z;
    }

    const float4* rp = (const float4*)(rad + (size_t)e * 8);
    float4 a = rp[0], b = rp[1];
    float r[8] = {a.x, a.y, a.z, a.w, b.x, b.y, b.z, b.w};
    float h[8];
    #pragma unroll
    for (int j = 0; j < 8; ++j) {
        float acc = 0.f;
        #pragma unroll
        for (int k = 0; k < 8; ++k) acc += r[k] * Wr1[k * 8 + j];
        h[j] = silu_f(acc * 0.35355339059327373f);  // 1/sqrt(8)
    }
    float4 ey = *(const float4*)(esh + (size_t)e * 4);
    int snd = senders[e];
    int rc = recv[e];
    int pos = starts[rc] + rank[e];
    int4 meta;
    meta.x = snd;
    meta.y = h22i(__floats2half2_rn(ey.y, ey.z));
    meta.z = h22i(__floats2half2_rn(ey.w, 0.f));
    meta.w = 0;
    int4 hp;
    hp.x = h22i(__floats2half2_rn(h[0], h[1]));
    hp.y = h22i(__floats2half2_rn(h[2], h[3]));
    hp.z = h22i(__floats2half2_rn(h[4], h[5]));
    hp.w = h22i(__floats2half2_rn(h[6], h[7]));
    records[2 * (size_t)pos] = meta;
    records[2 * (size_t)pos + 1] = hp;
}

// ---------------- per-edge accumulate helper ----------------
struct Acc {
    float S0, S1, Vv0, Vv1, Vv2, Vt0, Vt1, Vt2;
};
__device__ __forceinline__ void edge_accum(int4 meta, int4 hp, int2 q,
                                           const float* __restrict__ wr2a,
                                           const float* __restrict__ wr2b,
                                           const float* __restrict__ wr2c,
                                           const float* __restrict__ wr2d,
                                           Acc& A) {
    float2 h01 = __half22float2(i2h2(hp.x));
    float2 h23 = __half22float2(i2h2(hp.y));
    float2 h45 = __half22float2(i2h2(hp.z));
    float2 h67 = __half22float2(i2h2(hp.w));
    float h[8] = {h01.x, h01.y, h23.x, h23.y, h45.x, h45.y, h67.x, h67.y};
    float wss = 0.f, wvs = 0.f, wvt = 0.f, wst = 0.f;
    #pragma unroll
    for (int j = 0; j < 8; ++j) {
        wss += h[j] * wr2a[j];
        wvs += h[j] * wr2b[j];
        wvt += h[j] * wr2c[j];
        wst += h[j] * wr2d[j];
    }
    float2 y01 = __half22float2(i2h2(meta.y));
    float2 y2p = __half22float2(i2h2(meta.z));
    float y0 = y01.x, y1 = y01.y, y2 = y2p.x;
    float2 sv0 = __half22float2(i2h2(q.x));
    float2 v12 = __half22float2(i2h2(q.y));
    float ss = sv0.x, v0 = sv0.y, v1v = v12.x, v2 = v12.y;
    float dot = v0 * y0 + v1v * y1 + v2 * y2;
    A.S0 += ss * wss;
    A.S1 += dot * wst;
    A.Vv0 += v0 * wvs; A.Vv1 += v1v * wvs; A.Vv2 += v2 * wvs;
    float tv = ss * wvt;
    A.Vt0 += tv * y0; A.Vt1 += tv * y1; A.Vt2 += tv * y2;
}

// ---------------- K4: fused gather + message + down-proj + skip + gate ----------------
// One wave per node, 4 edges per iteration, predicate-free (edge lists padded to
// x4 with zero records; 16-record zero tail covers prefetch overrun). Two-stage
// software pipeline: records 2 iters ahead, up-rows 1 iter ahead. Barrier-free.
// NOTE: unroll 1 is load-bearing — unroll 2 doubled the live pipeline set past
// the 128-VGPR cap and spilled 176 MB of scratch traffic (R7 post-mortem).
__launch_bounds__(256, 4)
__global__ void k_gather(const __half* __restrict__ up_h,
                         const float* __restrict__ nf,
                         const int4* __restrict__ records,
                         const float* __restrict__ Wr2,
                         const int* __restrict__ starts,
                         const float* __restrict__ Wdns,
                         const float* __restrict__ Wdnv,
                         const float* __restrict__ Wsks,
                         const float* __restrict__ Wskv,
                         const int* __restrict__ species,
                         float* __restrict__ out) {
    __shared__ float agg[4][256];    // per node: S[64] then V[64][3] (m-major)
    __shared__ float snode[4][32];
    __shared__ float vnode[4][96];

    int tid = threadIdx.x;
    int w = tid >> 6;          // node slot 0..3 (== wave id)
    int lane = tid & 63;
    int sub = lane >> 5;       // edge sub-slot
    int m = lane & 31;         // channel
    int node = blockIdx.x * 4 + w;

    int s0 = starts[node], s1 = starts[node + 1];

    // ---- pipeline preheader (all loads unconditional; zero tail keeps them safe)
    int ta = s0 + sub;
    const int4* rp;
    rp = records + 2 * (size_t)ta;        int4 c0 = rp[0], c1 = rp[1];
    rp = records + 2 * (size_t)(ta + 2);  int4 d0 = rp[0], d1 = rp[1];

    // stage this wave's node_features for the skip connection (same-wave LDS)
    {
        const float* src = nf + (size_t)node * 128;
        #pragma unroll
        for (int it = 0; it < 2; ++it) {
            int c = lane + it * 64;
            float v = src[c];
            if (c < 32) snode[w][c] = v;
            else        vnode[w][c - 32] = v;
        }
    }

    int2 qa = *(const int2*)(up_h + (size_t)c0.x * 128 + m * 4);
    int2 qb = *(const int2*)(up_h + (size_t)d0.x * 128 + m * 4);

    rp = records + 2 * (size_t)(ta + 4);  int4 n0 = rp[0], n1 = rp[1];
    rp = records + 2 * (size_t)(ta + 6);  int4 e0 = rp[0], e1 = rp[1];

    // hoist Wr2 columns into registers; fold 1/sqrt(8) (and 1/sqrt(3) for wst)
    const float s8 = 0.35355339059327373f;
    const float s8s3 = 0.35355339059327373f * 0.5773502691896258f;
    float wr2a[8], wr2b[8], wr2c[8], wr2d[8];
    #pragma unroll
    for (int j = 0; j < 8; ++j) {
        wr2a[j] = Wr2[j * 128 + m] * s8;
        wr2b[j] = Wr2[j * 128 + 32 + m] * s8;
        wr2c[j] = Wr2[j * 128 + 64 + m] * s8;
        wr2d[j] = Wr2[j * 128 + 96 + m] * s8s3;
    }

    Acc A = {0.f,0.f,0.f,0.f,0.f,0.f,0.f,0.f};
    Acc B = {0.f,0.f,0.f,0.f,0.f,0.f,0.f,0.f};

    #pragma unroll 1
    for (int t0 = s0; t0 < s1; t0 += 4) {
        // up-row loads for next iteration (records already resident)
        int2 qna = *(const int2*)(up_h + (size_t)n0.x * 128 + m * 4);
        int2 qnb = *(const int2*)(up_h + (size_t)e0.x * 128 + m * 4);

        // record loads for iteration after next (may read zero tail — safe)
        int t2 = t0 + 8 + sub;
        rp = records + 2 * (size_t)t2;        int4 p0 = rp[0], p1 = rp[1];
        rp = records + 2 * (size_t)(t2 + 2);  int4 r0 = rp[0], r1 = rp[1];

        // compute current iteration (all operands already in registers)
        edge_accum(c0, c1, qa, wr2a, wr2b, wr2c, wr2d, A);
        edge_accum(d0, d1, qb, wr2a, wr2b, wr2c, wr2d, B);

        // rotate pipeline
        c0 = n0; c1 = n1; d0 = e0; d1 = e1;
        qa = qna; qb = qnb;
        n0 = p0; n1 = p1; e0 = r0; e1 = r1;
    }

    float accS0 = A.S0 + B.S0, accS1 = A.S1 + B.S1;
    float accVv0 = A.Vv0 + B.Vv0, accVv1 = A.Vv1 + B.Vv1, accVv2 = A.Vv2 + B.Vv2;
    float accVt0 = A.Vt0 + B.Vt0, accVt1 = A.Vt1 + B.Vt1, accVt2 = A.Vt2 + B.Vt2;

    // combine the two edge sub-slots
    accS0 += __shfl_xor(accS0, 32, 64);
    accS1 += __shfl_xor(accS1, 32, 64);
    accVv0 += __shfl_xor(accVv0, 32, 64);
    accVv1 += __shfl_xor(accVv1, 32, 64);
    accVv2 += __shfl_xor(accVv2, 32, 64);
    accVt0 += __shfl_xor(accVt0, 32, 64);
    accVt1 += __shfl_xor(accVt1, 32, 64);
    accVt2 += __shfl_xor(accVt2, 32, 64);

    const float inv_neigh = 0.25f;   // AVG_NEIGH^-0.5
    if (sub == 0) {
        agg[w][m]               = accS0 * inv_neigh;
        agg[w][32 + m]          = accS1 * inv_neigh;
        agg[w][64 + 3 * m + 0]  = accVv0 * inv_neigh;
        agg[w][64 + 3 * m + 1]  = accVv1 * inv_neigh;
        agg[w][64 + 3 * m + 2]  = accVv2 * inv_neigh;
        agg[w][160 + 3 * m + 0] = accVt0 * inv_neigh;
        agg[w][160 + 3 * m + 1] = accVt1 * inv_neigh;
        agg[w][160 + 3 * m + 2] = accVt2 * inv_neigh;
    }
    // same-wave LDS write->read: ordered per wave, no barrier needed

    const float* S = agg[w];
    const float* V = agg[w] + 64;
    int sp = species[node];

    // down projection split across the two half-waves (mm ranges), combined via shfl
    float gsa = 0.f, gsb = 0.f, gv0 = 0.f, gv1 = 0.f, gv2 = 0.f;
    {
        int mm0 = sub * 32;
        #pragma unroll 4
        for (int k = 0; k < 32; ++k) {
            int mm = mm0 + k;
            float Sm = S[mm];
            gsa += Sm * Wdns[mm * 64 + m];
            gsb += Sm * Wdns[mm * 64 + 32 + m];
            float wv = Wdnv[mm * 32 + m];
            gv0 += V[mm * 3 + 0] * wv;
            gv1 += V[mm * 3 + 1] * wv;
            gv2 += V[mm * 3 + 2] * wv;
        }
    }
    float ska = 0.f, skb = 0.f, skv0 = 0.f, skv1 = 0.f, skv2 = 0.f;
    {
        const float* Ws = Wsks + (size_t)sp * 2048;   // [32][64]
        const float* Wv = Wskv + (size_t)sp * 1024;   // [32][32]
        int mm0 = sub * 16;
        #pragma unroll 4
        for (int k = 0; k < 16; ++k) {
            int mm = mm0 + k;
            float sm = snode[w][mm];
            ska += sm * Ws[mm * 64 + m];
            skb += sm * Ws[mm * 64 + 32 + m];
            float wv = Wv[mm * 32 + m];
            skv0 += vnode[w][mm * 3 + 0] * wv;
            skv1 += vnode[w][mm * 3 + 1] * wv;
            skv2 += vnode[w][mm * 3 + 2] * wv;
        }
    }
    gsa += __shfl_xor(gsa, 32, 64);
    gsb += __shfl_xor(gsb, 32, 64);
    gv0 += __shfl_xor(gv0, 32, 64);
    gv1 += __shfl_xor(gv1, 32, 64);
    gv2 += __shfl_xor(gv2, 32, 64);
    ska += __shfl_xor(ska, 32, 64);
    skb += __shfl_xor(skb, 32, 64);
    skv0 += __shfl_xor(skv0, 32, 64);
    skv1 += __shfl_xor(skv1, 32, 64);
    skv2 += __shfl_xor(skv2, 32, 64);

    if (sub == 0) {
        const float inv8 = 0.125f;                 // (2*MUL)^-0.5
        const float isq32 = 0.17677669529663687f;  // 1/sqrt(32)
        float a  = 0.5f * (gsa * inv8 + ska * isq32);
        float b  = 0.5f * (gsb * inv8 + skb * isq32);
        float o0 = 0.5f * (gv0 * inv8 + skv0 * isq32);
        float o1 = 0.5f * (gv1 * inv8 + skv1 * isq32);
        float o2 = 0.5f * (gv2 * inv8 + skv2 * isq32);

        float feat = silu_f(a);
        float gate = silu_f(b);
        float* o = out + (size_t)node * 128;
        o[m] = feat;
        o[32 + 3 * m + 0] = o0 * gate;
        o[32 + 3 * m + 1] = o1 * gate;
        o[32 + 3 * m + 2] = o2 * gate;
    }
}

extern "C" void kernel_launch(void* const* d_in, const int* in_sizes, int n_in,
                              void* d_out, int out_size, void* d_ws, size_t ws_size,
                              hipStream_t stream) {
    const float* nf   = (const float*)d_in[0];
    const float* esh  = (const float*)d_in[1];
    const float* rad  = (const float*)d_in[2];
    const float* Wus  = (const float*)d_in[3];
    const float* Wuv  = (const float*)d_in[4];
    const float* Wr1  = (const float*)d_in[5];
    const float* Wr2  = (const float*)d_in[6];
    const float* Wdns = (const float*)d_in[7];
    const float* Wdnv = (const float*)d_in[8];
    const float* Wsks = (const float*)d_in[9];
    const float* Wskv = (const float*)d_in[10];
    const int* senders   = (const int*)d_in[11];
    const int* receivers = (const int*)d_in[12];
    const int* species   = (const int*)d_in[13];
    float* out = (float*)d_out;

    // workspace layout (bytes)
    char* ws = (char*)d_ws;
    __half* up_h   = (__half*)(ws);                       // 16384*128 f16   = 4 MB
    int4* records  = (int4*)(ws + (4u << 20));            // REC_CAP*32 B    ~ 10 MB
    int* counts    = (int*)(ws + (14u << 20));            // 64 KB
    int* starts    = (int*)(ws + (14u << 20) + 65536);    // 64 KB + 4
    int* rank      = (int*)(ws + (15u << 20));            // 1 MB

    hipMemsetAsync(counts, 0, 65536, stream);
    k_up<<<N_NODES / 2, 256, 0, stream>>>(nf, Wus, Wuv, up_h, receivers, counts, rank);
    k_scan<<<1, 1024, 0, stream>>>(counts, starts);
    k_edges<<<N_EDGES / 256, 256, 0, stream>>>(rad, Wr1, receivers, senders, esh,
                                               starts, counts, rank, records);
    k_gather<<<N_NODES / 4, 256, 0, stream>>>(up_h, nf, records, Wr2, starts,
                                              Wdns, Wdnv, Wsks, Wskv, species, out);
}